// Round 1
// baseline (1013.598 us; speedup 1.0000x reference)
//
#include <hip/hip_runtime.h>
#include <hip/hip_bf16.h>

// ScaledDotProductAttention: B=2,H=16,S=2048,D=64, T=8, outputs (O, attn) fp32.
// Two-pass flash-style: pass1 = row sums of exp(QK^T/T) (+ mask bits -> LDS),
// pass2 = recompute scores, write normalized attn, PV via MFMA.

using short4v = __attribute__((ext_vector_type(4))) short;
using short8v = __attribute__((ext_vector_type(8))) short;
using float4v = __attribute__((ext_vector_type(4))) float;

#define S_LEN 2048
#define D_DIM 64
#define QT 64                 // q rows per block
#define KTILE 64              // k cols per iteration
#define NIT (S_LEN / KTILE)   // 32
#define LDK 72                // padded LDS row stride (shorts): b128 reads -> 2-way (free)
#define ATTN_OFF (2 * 16 * 2048 * 64)   // B*H*S*D elements before attn in d_out

__device__ __forceinline__ short f2bf(float x) {
  __hip_bfloat16 h = __float2bfloat16(x);
  return __builtin_bit_cast(short, h);
}

__global__ __launch_bounds__(256) void sdpa_kernel(
    const float* __restrict__ q, const float* __restrict__ k,
    const float* __restrict__ v, const int* __restrict__ mask,
    float* __restrict__ out) {
  __shared__ short lds_k[KTILE * LDK];          // K tile, bf16 [krow][d]
  __shared__ short lds_vt[D_DIM * LDK];         // V tile transposed, bf16 [d][krow]
  __shared__ short lds_p[4 * 16 * LDK];         // per-wave P tiles [row][kcol]
  __shared__ unsigned short lds_mb[NIT * 256];  // pass1 mask bits (16/thread/iter)

  const int tid  = threadIdx.x;
  const int wave = tid >> 6;
  const int lane = tid & 63;
  const int quad = lane >> 4;
  const int l16  = lane & 15;

  const int blk = blockIdx.x;
  const int qt  = blk & (NIT - 1);  // S/QT == 32
  const int bh  = blk >> 5;
  const int b   = bh >> 4;

  const float* qp = q + (size_t)bh * S_LEN * D_DIM;
  const float* kp = k + (size_t)bh * S_LEN * D_DIM;
  const float* vp = v + (size_t)bh * S_LEN * D_DIM;
  const int*   mp = mask + (size_t)b * S_LEN * S_LEN;
  float* outO = out + (size_t)bh * S_LEN * D_DIM;
  float* outA = out + (size_t)ATTN_OFF + (size_t)bh * S_LEN * S_LEN;

  const int qbase = qt * QT;

  // ---- Q fragments, scale = log2(e)/8 folded in (exp -> single v_exp_f32) ----
  const float QSCALE = 0.18033688011112042f;  // 1.4426950408889634 / 8
  short8v qa[2];
  {
    const int qrow = qbase + wave * 16 + l16;  // A-operand: m = lane&15
    const float* src = qp + (size_t)qrow * D_DIM + quad * 8;
#pragma unroll
    for (int c = 0; c < 2; ++c) {
      float4v x0 = *(const float4v*)(src + c * 32);
      float4v x1 = *(const float4v*)(src + c * 32 + 4);
      short8v t;
      t[0] = f2bf(x0[0] * QSCALE); t[1] = f2bf(x0[1] * QSCALE);
      t[2] = f2bf(x0[2] * QSCALE); t[3] = f2bf(x0[3] * QSCALE);
      t[4] = f2bf(x1[0] * QSCALE); t[5] = f2bf(x1[1] * QSCALE);
      t[6] = f2bf(x1[2] * QSCALE); t[7] = f2bf(x1[3] * QSCALE);
      qa[c] = t;
    }
  }

  // ================= pass 1: row sums of exp =================
  float lsum[4] = {0.f, 0.f, 0.f, 0.f};

#pragma unroll 1
  for (int kt = 0; kt < NIT; ++kt) {
    // stage K tile -> LDS (flat float4 scheme, fully coalesced)
#pragma unroll
    for (int i = 0; i < 4; ++i) {
      int f = tid + i * 256;
      int row = f >> 4;
      int col = (f & 15) * 4;
      float4v x = *(const float4v*)(kp + (size_t)(kt * KTILE + row) * D_DIM + col);
      short4v y;
      y[0] = f2bf(x[0]); y[1] = f2bf(x[1]); y[2] = f2bf(x[2]); y[3] = f2bf(x[3]);
      *(short4v*)(lds_k + row * LDK + col) = y;
    }
    __syncthreads();

    unsigned mb = 0;
    const int qrowC = qbase + wave * 16 + quad * 4;  // C/D: row = quad*4+reg
#pragma unroll
    for (int t = 0; t < 4; ++t) {
      float4v acc = {0.f, 0.f, 0.f, 0.f};
#pragma unroll
      for (int c = 0; c < 2; ++c) {
        short8v bf = *(const short8v*)(lds_k + (t * 16 + l16) * LDK + c * 32 + quad * 8);
        acc = __builtin_amdgcn_mfma_f32_16x16x32_bf16(qa[c], bf, acc, 0, 0, 0);
      }
      const int kcol = kt * KTILE + t * 16 + l16;
      const int* mrow = mp + (size_t)qrowC * S_LEN + kcol;
#pragma unroll
      for (int r = 0; r < 4; ++r) {
        int mv = mrow[(size_t)r * S_LEN];
        float p = mv ? exp2f(acc[r]) : 0.f;
        lsum[r] += p;
        mb |= (mv ? 1u : 0u) << (t * 4 + r);
      }
    }
    lds_mb[kt * 256 + tid] = (unsigned short)mb;
    __syncthreads();
  }

  // row-sum reduce across the 16 lanes of each quad (xor 1,2,4,8 stays in quad)
  float invl[4];
#pragma unroll
  for (int r = 0; r < 4; ++r) {
    float s = lsum[r];
    s += __shfl_xor(s, 1);
    s += __shfl_xor(s, 2);
    s += __shfl_xor(s, 4);
    s += __shfl_xor(s, 8);
    invl[r] = 1.0f / s;
  }

  // ================= pass 2: attn write + PV =================
  float4v oacc[4];
#pragma unroll
  for (int dt = 0; dt < 4; ++dt) oacc[dt] = (float4v){0.f, 0.f, 0.f, 0.f};

#pragma unroll 1
  for (int kt = 0; kt < NIT; ++kt) {
    // stage K tile (again)
#pragma unroll
    for (int i = 0; i < 4; ++i) {
      int f = tid + i * 256;
      int row = f >> 4;
      int col = (f & 15) * 4;
      float4v x = *(const float4v*)(kp + (size_t)(kt * KTILE + row) * D_DIM + col);
      short4v y;
      y[0] = f2bf(x[0]); y[1] = f2bf(x[1]); y[2] = f2bf(x[2]); y[3] = f2bf(x[3]);
      *(short4v*)(lds_k + row * LDK + col) = y;
    }
    // stage V transposed: lds_vt[d][kr]  (coalesced dword reads along d)
    {
      const int d = tid & 63;
      const int krg = (tid >> 6) * 4;
#pragma unroll
      for (int i = 0; i < 4; ++i) {
        int kr0 = i * 16 + krg;
        short4v y;
#pragma unroll
        for (int j = 0; j < 4; ++j) {
          float x = vp[(size_t)(kt * KTILE + kr0 + j) * D_DIM + d];
          y[j] = f2bf(x);
        }
        *(short4v*)(lds_vt + d * LDK + kr0) = y;
      }
    }
    __syncthreads();

    const unsigned mb = lds_mb[kt * 256 + tid];
    const int qrowC = qbase + wave * 16 + quad * 4;
#pragma unroll
    for (int t = 0; t < 4; ++t) {
      float4v acc = {0.f, 0.f, 0.f, 0.f};
#pragma unroll
      for (int c = 0; c < 2; ++c) {
        short8v bf = *(const short8v*)(lds_k + (t * 16 + l16) * LDK + c * 32 + quad * 8);
        acc = __builtin_amdgcn_mfma_f32_16x16x32_bf16(qa[c], bf, acc, 0, 0, 0);
      }
      const int kcol = kt * KTILE + t * 16 + l16;
      float* arow = outA + (size_t)qrowC * S_LEN + kcol;
      short* prow = lds_p + (wave * 16 + quad * 4) * LDK + t * 16 + l16;
#pragma unroll
      for (int r = 0; r < 4; ++r) {
        float p = ((mb >> (t * 4 + r)) & 1u) ? exp2f(acc[r]) * invl[r] : 0.f;
        arow[(size_t)r * S_LEN] = p;      // attn out (fp32)
        prow[r * LDK] = f2bf(p);          // stage P for PV (C/D -> A layout via LDS)
      }
    }
    // PV: in-wave LDS RAW (DS pipe is in-order per wave; no barrier needed)
#pragma unroll
    for (int c = 0; c < 2; ++c) {
      short8v pa = *(const short8v*)(lds_p + (wave * 16 + l16) * LDK + c * 32 + quad * 8);
#pragma unroll
      for (int dt = 0; dt < 4; ++dt) {
        short8v vb = *(const short8v*)(lds_vt + (dt * 16 + l16) * LDK + c * 32 + quad * 8);
        oacc[dt] = __builtin_amdgcn_mfma_f32_16x16x32_bf16(pa, vb, oacc[dt], 0, 0, 0);
      }
    }
    __syncthreads();  // protect lds_k / lds_vt restage
  }

  // write O: tile dt covers cols dt*16+l16, rows quad*4+r
  {
    const int qrowC = qbase + wave * 16 + quad * 4;
    float* orow = outO + (size_t)qrowC * D_DIM + l16;
#pragma unroll
    for (int dt = 0; dt < 4; ++dt) {
#pragma unroll
      for (int r = 0; r < 4; ++r) {
        orow[(size_t)r * D_DIM + dt * 16] = oacc[dt][r];
      }
    }
  }
}

extern "C" void kernel_launch(void* const* d_in, const int* in_sizes, int n_in,
                              void* d_out, int out_size, void* d_ws, size_t ws_size,
                              hipStream_t stream) {
  const float* q = (const float*)d_in[0];
  const float* k = (const float*)d_in[1];
  const float* v = (const float*)d_in[2];
  const int* mask = (const int*)d_in[3];
  float* out = (float*)d_out;

  const int BH = 2 * 16;
  dim3 grid(BH * (S_LEN / QT));  // 1024 blocks
  dim3 block(256);
  sdpa_kernel<<<grid, block, 0, stream>>>(q, k, v, mask, out);
}

// Round 2
// 850.341 us; speedup vs baseline: 1.1920x; 1.1920x over previous
//
#include <hip/hip_runtime.h>
#include <hip/hip_bf16.h>

// ScaledDotProductAttention: B=2,H=16,S=2048,D=64, T=8, outputs (O, attn) fp32.
// Two-pass flash-style. R2: packed mask bitmask in d_ws (ballot pre-kernel),
// no lds_mb (LDS 44->27.6KB, 4 blocks/CU), vectorized attn writeback via lds_p.

using short4v = __attribute__((ext_vector_type(4))) short;
using short8v = __attribute__((ext_vector_type(8))) short;
using float4v = __attribute__((ext_vector_type(4))) float;

#define S_LEN 2048
#define D_DIM 64
#define QT 64                 // q rows per block
#define KTILE 64              // k cols per iteration
#define NIT (S_LEN / KTILE)   // 32
#define NW (S_LEN / 64)       // 32 packed 64-bit words per mask row
#define LDK 72                // padded LDS row stride (shorts)
#define ATTN_OFF (2 * 16 * 2048 * 64)

__device__ __forceinline__ short f2bf(float x) {
  __hip_bfloat16 h = __float2bfloat16(x);
  return __builtin_bit_cast(short, h);
}
__device__ __forceinline__ float bf2f(short s) {
  return __builtin_bit_cast(float, ((unsigned)(unsigned short)s) << 16);
}

// Pack mask int32 -> bitmask (64 cols per uint64). Fully coalesced ballot.
__global__ __launch_bounds__(256) void pack_mask_kernel(
    const int* __restrict__ mask, unsigned long long* __restrict__ pm, int nwords) {
  const int lane = threadIdx.x & 63;
  int gw = (blockIdx.x * blockDim.x + threadIdx.x) >> 6;
  const int stride = (gridDim.x * blockDim.x) >> 6;
  for (int w = gw; w < nwords; w += stride) {
    int m = mask[(size_t)w * 64 + lane];
    unsigned long long bits = __ballot(m != 0);
    if (lane == 0) pm[w] = bits;
  }
}

template <bool PACKED>
__global__ __launch_bounds__(256, 4) void sdpa_kernel(
    const float* __restrict__ q, const float* __restrict__ k,
    const float* __restrict__ v, const int* __restrict__ mask,
    const unsigned long long* __restrict__ pm, float* __restrict__ out) {
  __shared__ short lds_k[KTILE * LDK];   // K tile, bf16 [krow][d]
  __shared__ short lds_vt[D_DIM * LDK];  // V tile transposed, bf16 [d][krow]
  __shared__ short lds_p[QT * LDK];      // P tile bf16 [qrow][kcol] (per-wave rows)

  const int tid  = threadIdx.x;
  const int wave = tid >> 6;
  const int lane = tid & 63;
  const int quad = lane >> 4;
  const int l16  = lane & 15;

  const int blk = blockIdx.x;
  const int qt  = blk & (NIT - 1);
  const int bh  = blk >> 5;
  const int b   = bh >> 4;

  const float* qp = q + (size_t)bh * S_LEN * D_DIM;
  const float* kp = k + (size_t)bh * S_LEN * D_DIM;
  const float* vp = v + (size_t)bh * S_LEN * D_DIM;
  const int*   mp = mask + (size_t)b * S_LEN * S_LEN;
  float* outO = out + (size_t)bh * S_LEN * D_DIM;
  float* outA = out + (size_t)ATTN_OFF + (size_t)bh * S_LEN * S_LEN;

  const int qbase = qt * QT;
  const int qrowC = qbase + wave * 16 + quad * 4;  // C/D: row = quad*4 + reg

  // ---- Q fragments; scale log2(e)/8 folded in ----
  const float QSCALE = 0.18033688011112042f;
  short8v qa[2];
  {
    const int qrow = qbase + wave * 16 + l16;  // A-operand: m = lane&15
    const float* src = qp + (size_t)qrow * D_DIM + quad * 8;
#pragma unroll
    for (int c = 0; c < 2; ++c) {
      float4v x0 = *(const float4v*)(src + c * 32);
      float4v x1 = *(const float4v*)(src + c * 32 + 4);
      short8v t;
      t[0] = f2bf(x0[0] * QSCALE); t[1] = f2bf(x0[1] * QSCALE);
      t[2] = f2bf(x0[2] * QSCALE); t[3] = f2bf(x0[3] * QSCALE);
      t[4] = f2bf(x1[0] * QSCALE); t[5] = f2bf(x1[1] * QSCALE);
      t[6] = f2bf(x1[2] * QSCALE); t[7] = f2bf(x1[3] * QSCALE);
      qa[c] = t;
    }
  }

  // ================= pass 1: row sums of exp =================
  float lsum[4] = {0.f, 0.f, 0.f, 0.f};

#pragma unroll 1
  for (int kt = 0; kt < NIT; ++kt) {
#pragma unroll
    for (int i = 0; i < 4; ++i) {
      int f = tid + i * 256;
      int row = f >> 4;
      int col = (f & 15) * 4;
      float4v x = *(const float4v*)(kp + (size_t)(kt * KTILE + row) * D_DIM + col);
      short4v y;
      y[0] = f2bf(x[0]); y[1] = f2bf(x[1]); y[2] = f2bf(x[2]); y[3] = f2bf(x[3]);
      *(short4v*)(lds_k + row * LDK + col) = y;
    }
    __syncthreads();

    unsigned long long mrow[4];
    if (PACKED) {
#pragma unroll
      for (int r = 0; r < 4; ++r)
        mrow[r] = pm[((size_t)b * S_LEN + qrowC + r) * NW + kt];
    }
#pragma unroll
    for (int t = 0; t < 4; ++t) {
      float4v acc = {0.f, 0.f, 0.f, 0.f};
#pragma unroll
      for (int c = 0; c < 2; ++c) {
        short8v bf = *(const short8v*)(lds_k + (t * 16 + l16) * LDK + c * 32 + quad * 8);
        acc = __builtin_amdgcn_mfma_f32_16x16x32_bf16(qa[c], bf, acc, 0, 0, 0);
      }
      const int kcol = kt * KTILE + t * 16 + l16;
#pragma unroll
      for (int r = 0; r < 4; ++r) {
        bool mv = PACKED ? (((mrow[r] >> (t * 16 + l16)) & 1ull) != 0)
                         : (mp[(size_t)(qrowC + r) * S_LEN + kcol] != 0);
        float p = mv ? exp2f(acc[r]) : 0.f;
        lsum[r] += p;
      }
    }
    __syncthreads();
  }

  float invl[4];
#pragma unroll
  for (int r = 0; r < 4; ++r) {
    float s = lsum[r];
    s += __shfl_xor(s, 1);
    s += __shfl_xor(s, 2);
    s += __shfl_xor(s, 4);
    s += __shfl_xor(s, 8);
    invl[r] = 1.0f / s;
  }

  // ================= pass 2: attn write + PV =================
  float4v oacc[4];
#pragma unroll
  for (int dt = 0; dt < 4; ++dt) oacc[dt] = (float4v){0.f, 0.f, 0.f, 0.f};

#pragma unroll 1
  for (int kt = 0; kt < NIT; ++kt) {
#pragma unroll
    for (int i = 0; i < 4; ++i) {
      int f = tid + i * 256;
      int row = f >> 4;
      int col = (f & 15) * 4;
      float4v x = *(const float4v*)(kp + (size_t)(kt * KTILE + row) * D_DIM + col);
      short4v y;
      y[0] = f2bf(x[0]); y[1] = f2bf(x[1]); y[2] = f2bf(x[2]); y[3] = f2bf(x[3]);
      *(short4v*)(lds_k + row * LDK + col) = y;
    }
    {
      const int d = tid & 63;
      const int krg = (tid >> 6) * 4;
#pragma unroll
      for (int i = 0; i < 4; ++i) {
        int kr0 = i * 16 + krg;
        short4v y;
#pragma unroll
        for (int j = 0; j < 4; ++j) {
          float x = vp[(size_t)(kt * KTILE + kr0 + j) * D_DIM + d];
          y[j] = f2bf(x);
        }
        *(short4v*)(lds_vt + d * LDK + kr0) = y;
      }
    }
    __syncthreads();

    unsigned long long mrow[4];
    if (PACKED) {
#pragma unroll
      for (int r = 0; r < 4; ++r)
        mrow[r] = pm[((size_t)b * S_LEN + qrowC + r) * NW + kt];
    }
#pragma unroll
    for (int t = 0; t < 4; ++t) {
      float4v acc = {0.f, 0.f, 0.f, 0.f};
#pragma unroll
      for (int c = 0; c < 2; ++c) {
        short8v bf = *(const short8v*)(lds_k + (t * 16 + l16) * LDK + c * 32 + quad * 8);
        acc = __builtin_amdgcn_mfma_f32_16x16x32_bf16(qa[c], bf, acc, 0, 0, 0);
      }
      const int kcol = kt * KTILE + t * 16 + l16;
      short* prow = lds_p + (wave * 16 + quad * 4) * LDK + t * 16 + l16;
#pragma unroll
      for (int r = 0; r < 4; ++r) {
        bool mv = PACKED ? (((mrow[r] >> (t * 16 + l16)) & 1ull) != 0)
                         : (mp[(size_t)(qrowC + r) * S_LEN + kcol] != 0);
        float p = mv ? exp2f(acc[r]) * invl[r] : 0.f;
        prow[r * LDK] = f2bf(p);  // stage P (C/D -> A layout via LDS)
      }
    }

    // Same-wave readback (DS in-order per wave; rows wave*16.. written by this wave).
    // Vectorized attn writeback: 16 bf16 -> 4x dwordx4 fp32 stores per thread.
    {
      const int row16 = lane >> 2;
      const int cg = (lane & 3) * 16;
      const short* src = lds_p + (wave * 16 + row16) * LDK + cg;
      short8v p0 = *(const short8v*)src;
      short8v p1 = *(const short8v*)(src + 8);
      float* arow = outA + (size_t)(qbase + wave * 16 + row16) * S_LEN + kt * KTILE + cg;
      float4v f0 = {bf2f(p0[0]), bf2f(p0[1]), bf2f(p0[2]), bf2f(p0[3])};
      float4v f1 = {bf2f(p0[4]), bf2f(p0[5]), bf2f(p0[6]), bf2f(p0[7])};
      float4v f2 = {bf2f(p1[0]), bf2f(p1[1]), bf2f(p1[2]), bf2f(p1[3])};
      float4v f3 = {bf2f(p1[4]), bf2f(p1[5]), bf2f(p1[6]), bf2f(p1[7])};
      *(float4v*)(arow)      = f0;
      *(float4v*)(arow + 4)  = f1;
      *(float4v*)(arow + 8)  = f2;
      *(float4v*)(arow + 12) = f3;
    }

    // PV
#pragma unroll
    for (int c = 0; c < 2; ++c) {
      short8v pa = *(const short8v*)(lds_p + (wave * 16 + l16) * LDK + c * 32 + quad * 8);
#pragma unroll
      for (int dt = 0; dt < 4; ++dt) {
        short8v vb = *(const short8v*)(lds_vt + (dt * 16 + l16) * LDK + c * 32 + quad * 8);
        oacc[dt] = __builtin_amdgcn_mfma_f32_16x16x32_bf16(pa, vb, oacc[dt], 0, 0, 0);
      }
    }
    __syncthreads();  // protect lds_k / lds_vt / lds_p restage
  }

  {
    float* orow = outO + (size_t)qrowC * D_DIM + l16;
#pragma unroll
    for (int dt = 0; dt < 4; ++dt) {
#pragma unroll
      for (int r = 0; r < 4; ++r) {
        orow[(size_t)r * D_DIM + dt * 16] = oacc[dt][r];
      }
    }
  }
}

extern "C" void kernel_launch(void* const* d_in, const int* in_sizes, int n_in,
                              void* d_out, int out_size, void* d_ws, size_t ws_size,
                              hipStream_t stream) {
  const float* q = (const float*)d_in[0];
  const float* k = (const float*)d_in[1];
  const float* v = (const float*)d_in[2];
  const int* mask = (const int*)d_in[3];
  float* out = (float*)d_out;

  const int BH = 2 * 16;
  dim3 grid(BH * (S_LEN / QT));  // 1024 blocks
  dim3 block(256);

  const int nwords = 2 * S_LEN * NW;                 // 131072
  const size_t pm_bytes = (size_t)nwords * 8;        // 1 MiB
  if (ws_size >= pm_bytes) {
    unsigned long long* pm = (unsigned long long*)d_ws;
    pack_mask_kernel<<<256, 256, 0, stream>>>(mask, pm, nwords);
    sdpa_kernel<true><<<grid, block, 0, stream>>>(q, k, v, mask, pm, out);
  } else {
    sdpa_kernel<false><<<grid, block, 0, stream>>>(q, k, v, mask, nullptr, out);
  }
}